// Round 8
// baseline (156.038 us; speedup 1.0000x reference)
//
#include <hip/hip_runtime.h>
#include <math.h>

#define H 128
#define BLK 256
#define MMR 32  // rows per block in the GEMM pass (16 KB LDS)

__device__ inline float fast_tanh(float x) {
    return 1.0f - 2.0f / (__expf(2.0f * x) + 1.0f);
}

// ---------- CSR build ----------
__global__ void count_kernel(const int* __restrict__ dst, int* __restrict__ cnt, int E) {
    int e = blockIdx.x * blockDim.x + threadIdx.x;
    if (e < E) atomicAdd(&cnt[dst[e]], 1);
}

// wave-scan allocation of CSR segments (segment order arbitrary; gather uses off+cnt)
__global__ void alloc_kernel(const int* __restrict__ cnt, int* __restrict__ cursor,
                             int* __restrict__ off, int* __restrict__ total, int n) {
    int i = blockIdx.x * blockDim.x + threadIdx.x;
    int lane = threadIdx.x & 63;
    int v = (i < n) ? cnt[i] : 0;
    int pre = v;
    #pragma unroll
    for (int d = 1; d < 64; d <<= 1) {
        int t = __shfl_up(pre, d, 64);
        if (lane >= d) pre += t;
    }
    int wtot = __shfl(pre, 63, 64);
    int wbase = 0;
    if (lane == 63) wbase = atomicAdd(total, wtot);
    wbase = __shfl(wbase, 63, 64);
    int o = wbase + pre - v;
    if (i < n) { off[i] = o; cursor[i] = o; }
}

__global__ void fill_kernel(const int* __restrict__ src, const int* __restrict__ dst,
                            const int* __restrict__ rid,
                            int* __restrict__ cursor, int2* __restrict__ epack, int E) {
    int e = blockIdx.x * blockDim.x + threadIdx.x;
    if (e >= E) return;
    int d = dst[e];
    int pos = atomicAdd(&cursor[d], 1);  // cursor seeded with off[d]
    epack[pos] = make_int2(src[e], rid[e]);
}

// ---------- fused gather: 2 nodes per wave, 3-deep pipeline ----------
// wave = 2 nodes x 2 subgroups x 16 lanes; edges i+1 and i+2 prefetched
// while computing edge i.
__global__ void gather_kernel(const float* __restrict__ ent, const float* __restrict__ rel,
                              const int2* __restrict__ epack, const int* __restrict__ off,
                              const int* __restrict__ cnt,
                              float* __restrict__ neigh, int n_nodes) {
    int lane = threadIdx.x & 63;
    int wid = blockIdx.x * (blockDim.x >> 6) + (threadIdx.x >> 6);
    int half = lane >> 5;            // which node of the pair
    int node = wid * 2 + half;
    bool nvalid = node < n_nodes;
    int nodec = nvalid ? node : 0;
    int sg = (lane >> 4) & 1;        // subgroup within the node
    int gl = lane & 15;              // lane within subgroup: float4s gl*2, gl*2+1

    int beg = off[nodec];
    int deg = nvalid ? cnt[nodec] : 0;
    int degO = __shfl_xor(deg, 32, 64);
    int degM = max(deg, degO);       // wave-uniform loop bound

    const float4* crow = (const float4*)(ent + (size_t)nodec * H);
    float4 c0 = crow[gl * 2], c1 = crow[gl * 2 + 1];

    float m = -3.0e38f, s = 0.0f;
    float4 A0 = make_float4(0.f, 0.f, 0.f, 0.f), A1 = A0;

    for (int base = 0; base < degM; base += 32) {
        int2 my = make_int2(0, 0);
        if ((lane & 31) < deg - base) my = epack[beg + base + (lane & 31)];
        int remM = min(32, degM - base);
        int iters = (remM + 1) >> 1;

        // stage loads: E0 (compute next), E1, E2 prefetched
        int k0 = base + sg;
        bool v0 = (k0 < deg) && (k0 - base) < 32;
        float4 a0, a1, b0, b1;
        {
            int bl = half * 32 + (v0 ? (k0 - base) : 0);
            int sv = __shfl(my.x, bl, 64);
            int rv = __shfl(my.y, bl, 64);
            if (v0) {
                const float4* ar = (const float4*)(ent + (size_t)sv * H);
                const float4* br = (const float4*)(rel + (size_t)rv * H);
                a0 = ar[gl * 2]; a1 = ar[gl * 2 + 1];
                b0 = br[gl * 2]; b1 = br[gl * 2 + 1];
            }
        }
        int k1 = k0 + 2;
        bool v1 = (k1 < deg) && (k1 - base) < 32;
        float4 na0, na1, nb0, nb1;
        {
            int bl = half * 32 + (v1 ? (k1 - base) : 0);
            int sv = __shfl(my.x, bl, 64);
            int rv = __shfl(my.y, bl, 64);
            if (v1) {
                const float4* ar = (const float4*)(ent + (size_t)sv * H);
                const float4* br = (const float4*)(rel + (size_t)rv * H);
                na0 = ar[gl * 2]; na1 = ar[gl * 2 + 1];
                nb0 = br[gl * 2]; nb1 = br[gl * 2 + 1];
            }
        }
        for (int it = 0; it < iters; ++it) {
            // prefetch E2 (two edges ahead)
            int k2 = k0 + 4;
            bool v2 = (k2 < deg) && (k2 - base) < 32;
            float4 pa0, pa1, pb0, pb1;
            {
                int bl = half * 32 + (v2 ? (k2 - base) : 0);
                int sv = __shfl(my.x, bl, 64);
                int rv = __shfl(my.y, bl, 64);
                if (v2) {
                    const float4* ar = (const float4*)(ent + (size_t)sv * H);
                    const float4* br = (const float4*)(rel + (size_t)rv * H);
                    pa0 = ar[gl * 2]; pa1 = ar[gl * 2 + 1];
                    pb0 = br[gl * 2]; pb1 = br[gl * 2 + 1];
                }
            }
            if (v0) {
                float4 q0, q1;
                q0.x = a0.x + b0.x; q0.y = a0.y + b0.y; q0.z = a0.z + b0.z; q0.w = a0.w + b0.w;
                q1.x = a1.x + b1.x; q1.y = a1.y + b1.y; q1.z = a1.z + b1.z; q1.w = a1.w + b1.w;
                float p = q0.x * c0.x + q0.y * c0.y + q0.z * c0.z + q0.w * c0.w
                        + q1.x * c1.x + q1.y * c1.y + q1.z * c1.z + q1.w * c1.w;
                p += __shfl_xor(p, 1, 64);
                p += __shfl_xor(p, 2, 64);
                p += __shfl_xor(p, 4, 64);
                p += __shfl_xor(p, 8, 64);
                float M2 = fmaxf(m, p);
                float f = __expf(m - M2);
                float w = __expf(p - M2);
                m = M2;
                s = s * f + w;
                A0.x = A0.x * f + q0.x * w; A0.y = A0.y * f + q0.y * w;
                A0.z = A0.z * f + q0.z * w; A0.w = A0.w * f + q0.w * w;
                A1.x = A1.x * f + q1.x * w; A1.y = A1.y * f + q1.y * w;
                A1.z = A1.z * f + q1.z * w; A1.w = A1.w * f + q1.w * w;
            }
            a0 = na0; a1 = na1; b0 = nb0; b1 = nb1;
            na0 = pa0; na1 = pa1; nb0 = pb0; nb1 = pb1;
            v0 = v1; v1 = v2; k0 += 2;
        }
    }

    // single merge stage: subgroup 0 <-> subgroup 1 of the same node
    {
        float om = __shfl_xor(m, 16, 64);
        float os = __shfl_xor(s, 16, 64);
        float4 o0, o1;
        o0.x = __shfl_xor(A0.x, 16, 64); o0.y = __shfl_xor(A0.y, 16, 64);
        o0.z = __shfl_xor(A0.z, 16, 64); o0.w = __shfl_xor(A0.w, 16, 64);
        o1.x = __shfl_xor(A1.x, 16, 64); o1.y = __shfl_xor(A1.y, 16, 64);
        o1.z = __shfl_xor(A1.z, 16, 64); o1.w = __shfl_xor(A1.w, 16, 64);
        float M = fmaxf(m, om);
        float fs = __expf(m - M), fo = __expf(om - M);
        s = s * fs + os * fo;
        A0.x = A0.x * fs + o0.x * fo; A0.y = A0.y * fs + o0.y * fo;
        A0.z = A0.z * fs + o0.z * fo; A0.w = A0.w * fs + o0.w * fo;
        A1.x = A1.x * fs + o1.x * fo; A1.y = A1.y * fs + o1.y * fo;
        A1.z = A1.z * fs + o1.z * fo; A1.w = A1.w * fs + o1.w * fo;
    }
    float inv = (s > 0.0f) ? 1.0f / s : 0.0f;
    if (sg == 0 && nvalid) {
        float4* outr = (float4*)(neigh + (size_t)node * H);
        outr[gl * 2]     = make_float4(A0.x * inv, A0.y * inv, A0.z * inv, A0.w * inv);
        outr[gl * 2 + 1] = make_float4(A1.x * inv, A1.y * inv, A1.z * inv, A1.w * inv);
    }
}

// ---------- in-place tanh(neigh @ W) ----------
// rows in LDS (broadcast reads); W global with explicit register double-buffer
// so the L2 latency of the next W chunk hides under the current FMA block.
__global__ __launch_bounds__(256, 4) void mm_tanh_kernel(const float* __restrict__ W,
                                                         float* __restrict__ nodes, int n_nodes) {
    __shared__ float rows[MMR][H];  // 16 KB
    int t = threadIdx.x;
    int base = blockIdx.x * MMR;
    for (int i = t; i < MMR * (H / 4); i += 256) {
        int r = i >> 5;
        int c4 = i & 31;
        int n = base + r;
        float4 v = make_float4(0.f, 0.f, 0.f, 0.f);
        if (n < n_nodes) v = ((const float4*)(nodes + (size_t)n * H))[c4];
        ((float4*)rows[r])[c4] = v;
    }
    __syncthreads();

    int c0 = (t & 31) * 4;
    int r0 = (t >> 5) * 4;
    float acc[4][4] = {};
    float4 w[2][4];

    auto loadW = [&](int buf, int kk) {
        w[buf][0] = *(const float4*)(W + (size_t)(kk + 0) * H + c0);
        w[buf][1] = *(const float4*)(W + (size_t)(kk + 1) * H + c0);
        w[buf][2] = *(const float4*)(W + (size_t)(kk + 2) * H + c0);
        w[buf][3] = *(const float4*)(W + (size_t)(kk + 3) * H + c0);
    };
    auto compute = [&](int kk, int buf) {
        #pragma unroll
        for (int r = 0; r < 4; ++r) {
            float4 rv = *(const float4*)(&rows[r0 + r][kk]);
            acc[r][0] += rv.x * w[buf][0].x + rv.y * w[buf][1].x + rv.z * w[buf][2].x + rv.w * w[buf][3].x;
            acc[r][1] += rv.x * w[buf][0].y + rv.y * w[buf][1].y + rv.z * w[buf][2].y + rv.w * w[buf][3].y;
            acc[r][2] += rv.x * w[buf][0].z + rv.y * w[buf][1].z + rv.z * w[buf][2].z + rv.w * w[buf][3].z;
            acc[r][3] += rv.x * w[buf][0].w + rv.y * w[buf][1].w + rv.z * w[buf][2].w + rv.w * w[buf][3].w;
        }
    };

    loadW(0, 0);
    for (int k = 0; k < H; k += 8) {
        loadW(1, k + 4);        // prefetch next chunk before computing current
        compute(k, 0);
        if (k + 8 < H) loadW(0, k + 8);
        compute(k + 4, 1);
    }

    #pragma unroll
    for (int r = 0; r < 4; ++r) {
        int n = base + r0 + r;
        if (n < n_nodes) {
            float4 o;
            o.x = fast_tanh(acc[r][0]);
            o.y = fast_tanh(acc[r][1]);
            o.z = fast_tanh(acc[r][2]);
            o.w = fast_tanh(acc[r][3]);
            *(float4*)(nodes + (size_t)n * H + c0) = o;
        }
    }
}

extern "C" void kernel_launch(void* const* d_in, const int* in_sizes, int n_in,
                              void* d_out, int out_size, void* d_ws, size_t ws_size,
                              hipStream_t stream) {
    const float* ent = (const float*)d_in[0];
    const float* rel = (const float*)d_in[1];
    const float* W   = (const float*)d_in[2];
    const int* src   = (const int*)d_in[3];
    const int* dst   = (const int*)d_in[4];
    const int* rid   = (const int*)d_in[5];
    int n_nodes = in_sizes[0] / H;
    int n_edges = in_sizes[3];
    float* out = (float*)d_out;

    // ws layout (ints): cnt[N] | total[64 pad] | cursor[N] | off[N] | epack[2E]
    int* cnt    = (int*)d_ws;
    int* total  = cnt + n_nodes;
    int* cursor = total + 64;
    int* off    = cursor + n_nodes;
    int2* epack = (int2*)(off + n_nodes);

    hipMemsetAsync(cnt, 0, (size_t)(n_nodes + 64) * sizeof(int), stream);  // cnt + total
    count_kernel<<<(n_edges + BLK - 1) / BLK, BLK, 0, stream>>>(dst, cnt, n_edges);
    alloc_kernel<<<(n_nodes + BLK - 1) / BLK, BLK, 0, stream>>>(cnt, cursor, off, total, n_nodes);
    fill_kernel<<<(n_edges + BLK - 1) / BLK, BLK, 0, stream>>>(src, dst, rid, cursor, epack, n_edges);

    int n_waves = (n_nodes + 1) / 2;              // 2 nodes per wave
    const int wpb = 4;
    gather_kernel<<<(n_waves + wpb - 1) / wpb, wpb * 64, 0, stream>>>(ent, rel, epack, off, cnt, out, n_nodes);

    mm_tanh_kernel<<<(n_nodes + MMR - 1) / MMR, 256, 0, stream>>>(W, out, n_nodes);
}